// Round 1
// baseline (487.087 us; speedup 1.0000x reference)
//
#include <hip/hip_runtime.h>
#include <stdint.h>

#define KNN 16
#define CLEN 4
#define NB 4
#define NP 8192
#define CSPLIT 4
#define CHUNK (NP / CSPLIT)   // 2048 candidates per chunk-thread
#define QPB 64                // queries per block
#define TPB (QPB * CSPLIT)    // 256 threads

// FP-rounding variant switches to bit-match the XLA-CPU reference:
//   SQ_FMA:  sq = fma(z,z,fma(y,y,x*x))  vs  (x*x+y*y)+z*z
//   DOT_FMA: dot = fma chain (Eigen/oneDNN matmul)  vs  separate mul/add
// Round 1 guess: XLA elementwise without contraction (SQ_FMA=0),
// matmul library with FMA (DOT_FMA=1).
#define SQ_FMA 0
#define DOT_FMA 1

__global__ void prep_kernel(const float* __restrict__ xyz, float4* __restrict__ cand) {
#pragma clang fp contract(off)
  int t = blockIdx.x * blockDim.x + threadIdx.x;
  if (t >= NB * NP) return;
  float x = xyz[t * 3 + 0];
  float y = xyz[t * 3 + 1];
  float z = xyz[t * 3 + 2];
#if SQ_FMA
  float sq = fmaf(z, z, fmaf(y, y, x * x));
#else
  float sq = (x * x + y * y) + z * z;
#endif
  cand[t] = make_float4(x, y, z, sq);
}

// Branchless stable sorted-insert into ascending (dist[], idx[]) of size KNN.
// Insertion position = after all entries with d_existing <= d (all existing
// indices are smaller than the incoming index, so this reproduces
// jax.lax.top_k's lower-index-first tie-breaking exactly).
#define INSERT(dv, iv)                                         \
  do {                                                         \
    float _d = (dv); int _i = (iv);                            \
    _Pragma("unroll")                                          \
    for (int j = KNN - 1; j >= 1; --j) {                       \
      bool sh = dist[j - 1] > _d;                               \
      bool at = dist[j] > _d;                                   \
      dist[j] = sh ? dist[j - 1] : (at ? _d : dist[j]);         \
      idx[j]  = sh ? idx[j - 1]  : (at ? _i : idx[j]);          \
    }                                                          \
    if (dist[0] > _d) { dist[0] = _d; idx[0] = _i; }           \
  } while (0)

// Drain pending buffer, oldest first (preserves index-order stability).
#define FLUSH()                                                \
  do {                                                         \
    if (pc > 3) INSERT(pd3, pi3);                              \
    if (pc > 2) INSERT(pd2, pi2);                              \
    if (pc > 1) INSERT(pd1, pi1);                              \
    if (pc > 0) INSERT(pd0, pi0);                              \
    pc = 0;                                                    \
    dmax = dist[KNN - 1];                                      \
  } while (0)

__global__ __launch_bounds__(TPB) void knn_kernel(const float4* __restrict__ cand,
                                                  int* __restrict__ knn) {
#pragma clang fp contract(off)
  const int t = threadIdx.x;
  const int q_local = t & (QPB - 1);
  const int chunk = t >> 6;                 // wave index within block
  const int bq = blockIdx.x * QPB + q_local; // global (b*NP + n)
  const int b = bq >> 13;                    // NP == 8192
  const float4 qd = cand[bq];
  const float4* cb = cand + b * NP;

  float dist[KNN];
  int idx[KNN];
#pragma unroll
  for (int j = 0; j < KNN; ++j) { dist[j] = __builtin_inff(); idx[j] = 0; }
  float dmax = __builtin_inff();
  float pd0 = 0.f, pd1 = 0.f, pd2 = 0.f, pd3 = 0.f;
  int pi0 = 0, pi1 = 0, pi2 = 0, pi3 = 0;
  int pc = 0;

  const int m0 = chunk * CHUNK;
  for (int s = 0; s < CHUNK; ++s) {
    const int m = m0 + s;
    // all 64 lanes of a wave read the same candidate -> broadcast cacheline
    float4 c = cb[m];
    float p0 = qd.x * c.x;
#if DOT_FMA
    float dot = fmaf(qd.z, c.z, fmaf(qd.y, c.y, p0));
#else
    float dot = (p0 + qd.y * c.y) + qd.z * c.z;
#endif
    // 2*dot is exact (power of two), so fmaf(-2,dot,s) == rnd(s - rnd(2*dot))
    float d2 = fmaf(-2.0f, dot, qd.w + c.w);
    if (d2 < dmax) {          // quick reject vs stale 16th-best (insert is no-op-safe)
      pd3 = pd2; pi3 = pi2;
      pd2 = pd1; pi2 = pi1;
      pd1 = pd0; pi1 = pi0;
      pd0 = d2;  pi0 = m;
      ++pc;
    }
    if (__any(pc >= 4)) FLUSH();  // batch divergent inserts across the wave
  }
  FLUSH();

  // 4-way stable merge of per-chunk top-16 lists via LDS
  __shared__ float lds_d[TPB][KNN];
  __shared__ int lds_i[TPB][KNN];
#pragma unroll
  for (int j = 0; j < KNN; ++j) { lds_d[t][j] = dist[j]; lds_i[t][j] = idx[j]; }
  __syncthreads();

  if (t < QPB) {
    int p0_ = 0, p1_ = 0, p2_ = 0, p3_ = 0;
    int* kn = knn + bq * KNN;  // q_local == t here
    for (int j = 0; j < KNN; ++j) {
      int c0 = (p0_ < KNN) ? p0_ : 0;
      int c1 = (p1_ < KNN) ? p1_ : 0;
      int c2 = (p2_ < KNN) ? p2_ : 0;
      int c3 = (p3_ < KNN) ? p3_ : 0;
      float h0 = (p0_ < KNN) ? lds_d[t][c0]           : __builtin_inff();
      float h1 = (p1_ < KNN) ? lds_d[t + QPB][c1]     : __builtin_inff();
      float h2 = (p2_ < KNN) ? lds_d[t + 2 * QPB][c2] : __builtin_inff();
      float h3 = (p3_ < KNN) ? lds_d[t + 3 * QPB][c3] : __builtin_inff();
      int i0 = lds_i[t][c0];
      int i1 = lds_i[t + QPB][c1];
      int i2 = lds_i[t + 2 * QPB][c2];
      int i3 = lds_i[t + 3 * QPB][c3];
      // strict < keeps the earliest chunk on ties; chunk index ranges are
      // ascending, so this is exactly global lower-index-first stability.
      float bd = h0; int bi = i0; int bc = 0;
      if (h1 < bd) { bd = h1; bi = i1; bc = 1; }
      if (h2 < bd) { bd = h2; bi = i2; bc = 2; }
      if (h3 < bd) { bd = h3; bi = i3; bc = 3; }
      kn[j] = bi;
      p0_ += (bc == 0); p1_ += (bc == 1); p2_ += (bc == 2); p3_ += (bc == 3);
    }
  }
}

__global__ void walk_kernel(const int* __restrict__ rand_k, const int* __restrict__ knn,
                            int* __restrict__ out) {
  int t = blockIdx.x * blockDim.x + threadIdx.x;
  if (t >= NB * NP) return;
  int b = t >> 13;
  int n = t & (NP - 1);
  int cur = n;
  int* o = out + t * CLEN;
  o[0] = cur;
#pragma unroll
  for (int l = 0; l < CLEN - 1; ++l) {
    int rk = rand_k[(l * NB + b) * NP + n];
    cur = knn[(b * NP + cur) * KNN + rk];
    o[l + 1] = cur;
  }
}

extern "C" void kernel_launch(void* const* d_in, const int* in_sizes, int n_in,
                              void* d_out, int out_size, void* d_ws, size_t ws_size,
                              hipStream_t stream) {
  const float* xyz = (const float*)d_in[0];
  const int* rand_k = (const int*)d_in[1];
  int* out = (int*)d_out;

  float4* cand = (float4*)d_ws;                                   // 512 KB
  int* knn = (int*)((char*)d_ws + (size_t)NB * NP * sizeof(float4)); // 2 MB

  prep_kernel<<<(NB * NP + 255) / 256, 256, 0, stream>>>(xyz, cand);
  knn_kernel<<<(NB * NP) / QPB, TPB, 0, stream>>>(cand, knn);
  walk_kernel<<<(NB * NP + 255) / 256, 256, 0, stream>>>(rand_k, knn, out);
}

// Round 2
// 322.164 us; speedup vs baseline: 1.5119x; 1.5119x over previous
//
#include <hip/hip_runtime.h>
#include <stdint.h>

#define KNN 16
#define CLEN 4
#define NB 4
#define NP 8192
#define CSPLIT 8
#define CHUNK (NP / CSPLIT)   // 1024 candidates per chunk-thread
#define QPB 64                // queries per block
#define TPB (QPB * CSPLIT)    // 512 threads
#define SDEPTH 8              // per-lane LDS pending stack depth

// FP-rounding variants (verified bit-exact vs reference in round 1):
#define SQ_FMA 0
#define DOT_FMA 1

__global__ void prep_kernel(const float* __restrict__ xyz, float4* __restrict__ cand) {
#pragma clang fp contract(off)
  int t = blockIdx.x * blockDim.x + threadIdx.x;
  if (t >= NB * NP) return;
  float x = xyz[t * 3 + 0];
  float y = xyz[t * 3 + 1];
  float z = xyz[t * 3 + 2];
#if SQ_FMA
  float sq = fmaf(z, z, fmaf(y, y, x * x));
#else
  float sq = (x * x + y * y) + z * z;
#endif
  cand[t] = make_float4(x, y, z, sq);
}

// Branchless stable sorted-insert into ascending (dist[], idx[]) of size KNN.
// Insert after all entries with d_existing <= d; existing entries were pushed
// in ascending global index order, so this reproduces jax.lax.top_k's
// lower-index-first tie-breaking exactly (lexicographic (d, idx) select).
#define INSERT(dv, iv)                                         \
  do {                                                         \
    float _d = (dv); int _i = (iv);                            \
    _Pragma("unroll")                                          \
    for (int j = KNN - 1; j >= 1; --j) {                       \
      bool sh = dist[j - 1] > _d;                               \
      bool at = dist[j] > _d;                                   \
      dist[j] = sh ? dist[j - 1] : (at ? _d : dist[j]);         \
      idx[j]  = sh ? idx[j - 1]  : (at ? _i : idx[j]);          \
    }                                                          \
    if (dist[0] > _d) { dist[0] = _d; idx[0] = _i; }           \
  } while (0)

// Depth-adaptive drain of the LDS pending stack, oldest slot first
// (preserves ascending-index stability). Inactive lanes insert +inf (no-op).
#define FLUSH()                                                \
  do {                                                         \
    _Pragma("unroll 1")                                        \
    for (int j = 0; j < SDEPTH; ++j) {                         \
      if (!__any(j < pc)) break;                               \
      bool act = j < pc;                                       \
      float fd = act ? stk_d[j][t] : __builtin_inff();         \
      int  fi = act ? stk_i[j][t] : 0;                          \
      INSERT(fd, fi);                                          \
    }                                                          \
    pc = 0;                                                    \
    dmax = dist[KNN - 1];                                      \
  } while (0)

__global__ __launch_bounds__(TPB, 4) void knn_kernel(const float4* __restrict__ cand,
                                                     int* __restrict__ knn) {
#pragma clang fp contract(off)
  // 64 KB shared, aliased: phase 1 = pending stacks (32 KB), phase 2 = merge lists (64 KB)
  __shared__ __align__(16) char smem[65536];
  float (*stk_d)[TPB] = (float (*)[TPB])smem;                 // [SDEPTH][TPB] 16 KB
  int   (*stk_i)[TPB] = (int (*)[TPB])(smem + 16384);         // [SDEPTH][TPB] 16 KB

  const int t = threadIdx.x;
  const int q_local = t & (QPB - 1);
  const int chunk = t >> 6;                  // wave index within block
  const int bq = blockIdx.x * QPB + q_local; // global (b*NP + n)
  const int b = bq >> 13;                    // NP == 8192
  const float4 qd = cand[bq];
  const float4* cb = cand + b * NP;

  float dist[KNN];
  int idx[KNN];
#pragma unroll
  for (int j = 0; j < KNN; ++j) { dist[j] = __builtin_inff(); idx[j] = 0; }
  float dmax = __builtin_inff();
  int pc = 0;

  const int m0 = chunk * CHUNK;
  for (int s = 0; s < CHUNK; s += 4) {
    // 4 independent broadcast loads in flight (all 64 lanes same address)
    float4 c0 = cb[m0 + s + 0];
    float4 c1 = cb[m0 + s + 1];
    float4 c2 = cb[m0 + s + 2];
    float4 c3 = cb[m0 + s + 3];
#define PROC(cc, mm)                                                \
    do {                                                            \
      float p0 = qd.x * (cc).x;                                     \
      float dot = fmaf(qd.z, (cc).z, fmaf(qd.y, (cc).y, p0));       \
      float d2 = fmaf(-2.0f, dot, qd.w + (cc).w);                   \
      if (d2 < dmax) { /* exec-masked rare path */                  \
        stk_d[pc][t] = d2;                                          \
        stk_i[pc][t] = (mm);                                        \
        ++pc;                                                       \
      }                                                             \
    } while (0)
    PROC(c0, m0 + s + 0);
    PROC(c1, m0 + s + 1);
    PROC(c2, m0 + s + 2);
    PROC(c3, m0 + s + 3);
#undef PROC
    // post-flush pc<=0; each 4-group adds <=4; flush at >=5 keeps pc<=SDEPTH
    if (__any(pc >= SDEPTH - 3)) FLUSH();
  }
  FLUSH();

  __syncthreads();  // done with stacks; repurpose smem for merge lists
  float (*ld)[KNN] = (float (*)[KNN])smem;                    // [TPB][KNN] 32 KB
  int   (*li)[KNN] = (int (*)[KNN])(smem + 32768);            // [TPB][KNN] 32 KB
#pragma unroll
  for (int j = 0; j < KNN; ++j) { ld[t][j] = dist[j]; li[t][j] = idx[j]; }
  __syncthreads();

  // 8-way stable merge (strict < keeps lowest chunk on ties; chunk index
  // ranges ascend, so this is global lower-index-first stability).
  if (t < QPB) {
    int p[CSPLIT];
#pragma unroll
    for (int c = 0; c < CSPLIT; ++c) p[c] = 0;
    int* kn = knn + bq * KNN;
    for (int j = 0; j < KNN; ++j) {
      float bd = __builtin_inff();
      int bi = 0, bc = 0;
#pragma unroll
      for (int c = 0; c < CSPLIT; ++c) {
        bool v = p[c] < KNN;
        int pp = v ? p[c] : 0;
        float hd = v ? ld[t + c * QPB][pp] : __builtin_inff();
        int hi = li[t + c * QPB][pp];
        if (hd < bd) { bd = hd; bi = hi; bc = c; }
      }
      kn[j] = bi;
#pragma unroll
      for (int c = 0; c < CSPLIT; ++c) p[c] += (bc == c);
    }
  }
}

__global__ void walk_kernel(const int* __restrict__ rand_k, const int* __restrict__ knn,
                            int* __restrict__ out) {
  int t = blockIdx.x * blockDim.x + threadIdx.x;
  if (t >= NB * NP) return;
  int b = t >> 13;
  int n = t & (NP - 1);
  int cur = n;
  int* o = out + t * CLEN;
  o[0] = cur;
#pragma unroll
  for (int l = 0; l < CLEN - 1; ++l) {
    int rk = rand_k[(l * NB + b) * NP + n];
    cur = knn[(b * NP + cur) * KNN + rk];
    o[l + 1] = cur;
  }
}

extern "C" void kernel_launch(void* const* d_in, const int* in_sizes, int n_in,
                              void* d_out, int out_size, void* d_ws, size_t ws_size,
                              hipStream_t stream) {
  const float* xyz = (const float*)d_in[0];
  const int* rand_k = (const int*)d_in[1];
  int* out = (int*)d_out;

  float4* cand = (float4*)d_ws;                                      // 512 KB
  int* knn = (int*)((char*)d_ws + (size_t)NB * NP * sizeof(float4)); // 2 MB

  prep_kernel<<<(NB * NP + 255) / 256, 256, 0, stream>>>(xyz, cand);
  knn_kernel<<<(NB * NP) / QPB, TPB, 0, stream>>>(cand, knn);
  walk_kernel<<<(NB * NP + 255) / 256, 256, 0, stream>>>(rand_k, knn, out);
}

// Round 3
// 203.276 us; speedup vs baseline: 2.3962x; 1.5849x over previous
//
#include <hip/hip_runtime.h>
#include <stdint.h>

#define KNN 16
#define CLEN 4
#define NB 4
#define NP 8192
#define CSPLIT 8
#define CHUNK (NP / CSPLIT)   // 1024 candidates per chunk-thread
#define QPB 64                // queries per block
#define TPB (QPB * CSPLIT)    // 512 threads
#define SDEPTH 12             // per-lane LDS pending stack depth

// FP-rounding variants (verified bit-exact vs reference in round 1):
#define SQ_FMA 0
#define DOT_FMA 1

__global__ void prep_kernel(const float* __restrict__ xyz, float4* __restrict__ cand) {
#pragma clang fp contract(off)
  int t = blockIdx.x * blockDim.x + threadIdx.x;
  if (t >= NB * NP) return;
  float x = xyz[t * 3 + 0];
  float y = xyz[t * 3 + 1];
  float z = xyz[t * 3 + 2];
#if SQ_FMA
  float sq = fmaf(z, z, fmaf(y, y, x * x));
#else
  float sq = (x * x + y * y) + z * z;
#endif
  cand[t] = make_float4(x, y, z, sq);
}

// Stable sorted-insert into ascending (dist[], idx[]), med3 encoding.
// dist[j]_new = median(dist[j-1], dist[j], d) == shift/insert/keep cases of the
// classic chain (values are pure copies -> bit-identical to the verified R1
// version). Compares c[j] = dist[j] > d are shared with the idx chain; strict >
// places d after equals, and since entries arrive in ascending global index
// order this reproduces jax.lax.top_k lower-index-first tie-breaking exactly.
#define INSERT(dv, iv)                                              \
  do {                                                              \
    float _d = (dv); int _i = (iv);                                 \
    bool c[KNN];                                                    \
    _Pragma("unroll")                                               \
    for (int j = 0; j < KNN; ++j) c[j] = dist[j] > _d;              \
    _Pragma("unroll")                                               \
    for (int j = KNN - 1; j >= 1; --j) {                            \
      dist[j] = __builtin_amdgcn_fmed3f(dist[j - 1], dist[j], _d);  \
      idx[j] = c[j - 1] ? idx[j - 1] : (c[j] ? _i : idx[j]);        \
    }                                                               \
    dist[0] = fminf(dist[0], _d);                                   \
    idx[0] = c[0] ? _i : idx[0];                                    \
  } while (0)

// Depth-adaptive drain of the LDS pending stack, oldest slot first
// (preserves ascending-index stability). Inactive lanes insert +inf (no-op).
#define FLUSH()                                                \
  do {                                                         \
    _Pragma("unroll 1")                                        \
    for (int j = 0; j < SDEPTH; ++j) {                         \
      if (!__any(j < pc)) break;                               \
      bool act = j < pc;                                       \
      float2 e = stk[j * TPB + t];                             \
      float fd = act ? e.x : __builtin_inff();                 \
      int fi = __float_as_int(e.y);                            \
      INSERT(fd, fi);                                          \
    }                                                          \
    pc = 0;                                                    \
    dmax = dist[KNN - 1];                                      \
  } while (0)

__global__ __launch_bounds__(TPB, 6) void knn_kernel(const float4* __restrict__ cand,
                                                     int* __restrict__ knn) {
#pragma clang fp contract(off)
  // 48 KB shared, aliased:
  //   phase 1: pending stacks  [SDEPTH][TPB] float2 = 48 KB
  //   phase 2a: lists for chunks 0-3 [4*QPB][KNN] float2 = 32 KB  (+ alist 8 KB @32K)
  //   phase 2b: lists for chunks 4-7 reuse [0,32K)
  __shared__ __align__(16) char smem[49152];
  float2* stk = (float2*)smem;

  const int t = threadIdx.x;
  const int q_local = t & (QPB - 1);
  const int chunk = t >> 6;                  // wave index within block
  const int bq = blockIdx.x * QPB + q_local; // global (b*NP + n)
  const int b = bq >> 13;                    // NP == 8192
  const float4 qd = cand[bq];
  const float4* cb = cand + b * NP;

  float dist[KNN];
  int idx[KNN];
#pragma unroll
  for (int j = 0; j < KNN; ++j) { dist[j] = __builtin_inff(); idx[j] = 0; }
  float dmax = __builtin_inff();
  int pc = 0;

  const int m0 = chunk * CHUNK;
  for (int s = 0; s < CHUNK; s += 4) {
    // 4 independent broadcast loads in flight (all 64 lanes same address)
    float4 c0 = cb[m0 + s + 0];
    float4 c1 = cb[m0 + s + 1];
    float4 c2 = cb[m0 + s + 2];
    float4 c3 = cb[m0 + s + 3];
#define PROC(cc, mm)                                                \
    do {                                                            \
      float p0 = qd.x * (cc).x;                                     \
      float dot = fmaf(qd.z, (cc).z, fmaf(qd.y, (cc).y, p0));       \
      float d2 = fmaf(-2.0f, dot, qd.w + (cc).w);                   \
      if (d2 < dmax) { /* exec-masked rare path */                  \
        stk[pc * TPB + t] = make_float2(d2, __int_as_float(mm));    \
        ++pc;                                                       \
      }                                                             \
    } while (0)
    PROC(c0, m0 + s + 0);
    PROC(c1, m0 + s + 1);
    PROC(c2, m0 + s + 2);
    PROC(c3, m0 + s + 3);
#undef PROC
    // post-flush pc==0; each 4-group adds <=4; flush at >=9 keeps pc<=SDEPTH
    if (__any(pc >= SDEPTH - 3)) FLUSH();
  }
  FLUSH();

  __syncthreads();  // all waves done with stacks; repurpose smem for merging
  float2* lists = (float2*)smem;            // [4*QPB][KNN] = 32 KB
  float2* alist = (float2*)(smem + 32768);  // [QPB][KNN]   =  8 KB

  // ---- phase A: chunks 0..3 publish, 4-way stable merge -> alist ----
  if (chunk < 4) {
#pragma unroll
    for (int j = 0; j < KNN; ++j)
      lists[t * KNN + j] = make_float2(dist[j], __int_as_float(idx[j]));
  }
  __syncthreads();
  if (t < QPB) {
    int p[4] = {0, 0, 0, 0};
#pragma unroll 1
    for (int j = 0; j < KNN; ++j) {
      float bd = __builtin_inff();
      int bi = 0, bc = 0;
#pragma unroll
      for (int c = 0; c < 4; ++c) {
        bool v = p[c] < KNN;
        int pp = v ? p[c] : 0;
        float2 e = lists[(t + c * QPB) * KNN + pp];
        float hd = v ? e.x : __builtin_inff();
        // strict < keeps the earliest chunk on ties (ascending index ranges)
        if (hd < bd || c == 0) { bd = hd; bi = __float_as_int(e.y); bc = c; }
      }
      alist[t * KNN + j] = make_float2(bd, __int_as_float(bi));
#pragma unroll
      for (int c = 0; c < 4; ++c) p[c] += (bc == c);
    }
  }
  __syncthreads();

  // ---- phase B: chunks 4..7 publish (reuse region), 5-way merge -> out ----
  if (chunk >= 4) {
#pragma unroll
    for (int j = 0; j < KNN; ++j)
      lists[(t - 4 * QPB) * KNN + j] = make_float2(dist[j], __int_as_float(idx[j]));
  }
  __syncthreads();
  if (t < QPB) {
    int p[5] = {0, 0, 0, 0, 0};  // 0 = alist (chunks 0-3), 1..4 = chunks 4..7
    int* kn = knn + bq * KNN;
#pragma unroll 1
    for (int j = 0; j < KNN; ++j) {
      float bd;
      int bi, bc;
      {
        bool v = p[0] < KNN;
        int pp = v ? p[0] : 0;
        float2 e = alist[t * KNN + pp];
        bd = v ? e.x : __builtin_inff();
        bi = __float_as_int(e.y);
        bc = 0;
      }
#pragma unroll
      for (int c = 0; c < 4; ++c) {
        bool v = p[c + 1] < KNN;
        int pp = v ? p[c + 1] : 0;
        float2 e = lists[(t + c * QPB) * KNN + pp];
        float hd = v ? e.x : __builtin_inff();
        if (hd < bd) { bd = hd; bi = __float_as_int(e.y); bc = c + 1; }
      }
      kn[j] = bi;
#pragma unroll
      for (int c = 0; c < 5; ++c) p[c] += (bc == c);
    }
  }
}

__global__ void walk_kernel(const int* __restrict__ rand_k, const int* __restrict__ knn,
                            int* __restrict__ out) {
  int t = blockIdx.x * blockDim.x + threadIdx.x;
  if (t >= NB * NP) return;
  int b = t >> 13;
  int n = t & (NP - 1);
  int cur = n;
  int* o = out + t * CLEN;
  o[0] = cur;
#pragma unroll
  for (int l = 0; l < CLEN - 1; ++l) {
    int rk = rand_k[(l * NB + b) * NP + n];
    cur = knn[(b * NP + cur) * KNN + rk];
    o[l + 1] = cur;
  }
}

extern "C" void kernel_launch(void* const* d_in, const int* in_sizes, int n_in,
                              void* d_out, int out_size, void* d_ws, size_t ws_size,
                              hipStream_t stream) {
  const float* xyz = (const float*)d_in[0];
  const int* rand_k = (const int*)d_in[1];
  int* out = (int*)d_out;

  float4* cand = (float4*)d_ws;                                      // 512 KB
  int* knn = (int*)((char*)d_ws + (size_t)NB * NP * sizeof(float4)); // 2 MB

  prep_kernel<<<(NB * NP + 255) / 256, 256, 0, stream>>>(xyz, cand);
  knn_kernel<<<(NB * NP) / QPB, TPB, 0, stream>>>(cand, knn);
  walk_kernel<<<(NB * NP + 255) / 256, 256, 0, stream>>>(rand_k, knn, out);
}

// Round 4
// 188.083 us; speedup vs baseline: 2.5897x; 1.0808x over previous
//
#include <hip/hip_runtime.h>
#include <stdint.h>

#define KNN 16
#define CLEN 4
#define NB 4
#define NP 8192
#define CSPLIT 8
#define CHUNK (NP / CSPLIT)   // 1024 candidates per chunk-thread
#define QPB 64                // queries per block
#define TPB (QPB * CSPLIT)    // 512 threads
#define SDEPTH 12             // per-lane LDS pending stack depth

// FP-rounding variants (verified bit-exact vs reference in round 1):
#define SQ_FMA 0
#define DOT_FMA 1

__global__ void prep_kernel(const float* __restrict__ xyz, float4* __restrict__ cand) {
#pragma clang fp contract(off)
  int t = blockIdx.x * blockDim.x + threadIdx.x;
  if (t >= NB * NP) return;
  float x = xyz[t * 3 + 0];
  float y = xyz[t * 3 + 1];
  float z = xyz[t * 3 + 2];
#if SQ_FMA
  float sq = fmaf(z, z, fmaf(y, y, x * x));
#else
  float sq = (x * x + y * y) + z * z;
#endif
  cand[t] = make_float4(x, y, z, sq);
}

// Stable sorted-insert into ascending (dist[], idx[]), med3 encoding
// (verified bit-exact in rounds 1-2). Strict > places d after equals; entries
// arrive in ascending global index order -> exact top_k tie semantics.
#define INSERT(dv, iv)                                              \
  do {                                                              \
    float _d = (dv); int _i = (iv);                                 \
    bool c[KNN];                                                    \
    _Pragma("unroll")                                               \
    for (int j = 0; j < KNN; ++j) c[j] = dist[j] > _d;              \
    _Pragma("unroll")                                               \
    for (int j = KNN - 1; j >= 1; --j) {                            \
      dist[j] = __builtin_amdgcn_fmed3f(dist[j - 1], dist[j], _d);  \
      idx[j] = c[j - 1] ? idx[j - 1] : (c[j] ? _i : idx[j]);        \
    }                                                               \
    dist[0] = fminf(dist[0], _d);                                   \
    idx[0] = c[0] ? _i : idx[0];                                    \
  } while (0)

// Batched drain: issue ALL stack reads first (independent b64s, conflict-free
// lane-consecutive layout), then register-only INSERTs oldest-first with a
// depth-adaptive early-out. Garbage slots (j >= pc) insert +inf (no-op).
#define FLUSH()                                                \
  do {                                                         \
    float2 e[SDEPTH];                                          \
    _Pragma("unroll")                                          \
    for (int j = 0; j < SDEPTH; ++j) e[j] = stk[j * TPB + t];  \
    _Pragma("unroll")                                          \
    for (int j = 0; j < SDEPTH; ++j) {                         \
      if (!__any(j < pc)) break;                               \
      bool act = j < pc;                                       \
      float fd = act ? e[j].x : __builtin_inff();              \
      int fi = __float_as_int(e[j].y);                         \
      INSERT(fd, fi);                                          \
    }                                                          \
    pc = 0;                                                    \
    dmax = dist[KNN - 1];                                      \
  } while (0)

__global__ __launch_bounds__(TPB, 4) void knn_kernel(const float4* __restrict__ cand,
                                                     int* __restrict__ knn) {
#pragma clang fp contract(off)
  // 48 KB shared, aliased:
  //   phase 1: pending stacks  [SDEPTH][TPB] float2 = 48 KB
  //   phase 2: transposed merge lists tl[KNN][4*QPB] f2 = 32 KB, alist[KNN][QPB] f2 = 8 KB
  __shared__ __align__(16) char smem[49152];
  float2* stk = (float2*)smem;

  const int t = threadIdx.x;
  const int q_local = t & (QPB - 1);
  const int chunk = t >> 6;                  // wave index within block
  const int bq = blockIdx.x * QPB + q_local; // global (b*NP + n)
  const int b = bq >> 13;                    // NP == 8192
  const float4 qd = cand[bq];
  const float4* cb = cand + b * NP;

  float dist[KNN];
  int idx[KNN];
#pragma unroll
  for (int j = 0; j < KNN; ++j) { dist[j] = __builtin_inff(); idx[j] = 0; }
  float dmax = __builtin_inff();
  int pc = 0;

  const int m0 = chunk * CHUNK;
  for (int s = 0; s < CHUNK; s += 8) {
    // 8 independent broadcast loads in flight (all 64 lanes same address)
    float4 c0 = cb[m0 + s + 0];
    float4 c1 = cb[m0 + s + 1];
    float4 c2 = cb[m0 + s + 2];
    float4 c3 = cb[m0 + s + 3];
    float4 c4 = cb[m0 + s + 4];
    float4 c5 = cb[m0 + s + 5];
    float4 c6 = cb[m0 + s + 6];
    float4 c7 = cb[m0 + s + 7];
#define PROC(cc, mm)                                                \
    do {                                                            \
      float p0 = qd.x * (cc).x;                                     \
      float dot = fmaf(qd.z, (cc).z, fmaf(qd.y, (cc).y, p0));       \
      float d2 = fmaf(-2.0f, dot, qd.w + (cc).w);                   \
      if (d2 < dmax) { /* exec-masked rare path */                  \
        stk[pc * TPB + t] = make_float2(d2, __int_as_float(mm));    \
        ++pc;                                                       \
      }                                                             \
    } while (0)
    PROC(c0, m0 + s + 0);
    PROC(c1, m0 + s + 1);
    PROC(c2, m0 + s + 2);
    PROC(c3, m0 + s + 3);
    // post-flush pc==0; each quad adds <=4; flush at >=9 keeps pc<=SDEPTH
    if (__any(pc >= SDEPTH - 3)) FLUSH();
    PROC(c4, m0 + s + 4);
    PROC(c5, m0 + s + 5);
    PROC(c6, m0 + s + 6);
    PROC(c7, m0 + s + 7);
    if (__any(pc >= SDEPTH - 3)) FLUSH();
#undef PROC
  }
  FLUSH();

  __syncthreads();  // all waves done with stacks; repurpose smem for merging
  // Transposed lists: row j, column = query-slot. Lane-consecutive columns ->
  // conflict-free publishes and merge reads (was a 64-way conflict in R2).
  float2* tl = (float2*)smem;               // [KNN][4*QPB] = 32 KB
  float2* al = (float2*)(smem + 32768);     // [KNN][QPB]   =  8 KB

  // ---- phase A: chunks 0..3 publish, 4-way stable merge -> al ----
  if (chunk < 4) {
#pragma unroll
    for (int j = 0; j < KNN; ++j)
      tl[j * (4 * QPB) + t] = make_float2(dist[j], __int_as_float(idx[j]));
  }
  __syncthreads();
  if (t < QPB) {
    int p[4] = {0, 0, 0, 0};
#pragma unroll 1
    for (int j = 0; j < KNN; ++j) {
      float bd = __builtin_inff();
      int bi = 0, bc = 0;
#pragma unroll
      for (int c = 0; c < 4; ++c) {
        bool v = p[c] < KNN;
        int pp = v ? p[c] : 0;
        float2 e = tl[pp * (4 * QPB) + t + c * QPB];
        float hd = v ? e.x : __builtin_inff();
        // strict < keeps the earliest chunk on ties (ascending index ranges)
        if (hd < bd || c == 0) { bd = hd; bi = __float_as_int(e.y); bc = c; }
      }
      al[j * QPB + t] = make_float2(bd, __int_as_float(bi));
#pragma unroll
      for (int c = 0; c < 4; ++c) p[c] += (bc == c);
    }
  }
  __syncthreads();

  // ---- phase B: chunks 4..7 publish (reuse region), 5-way merge -> out ----
  if (chunk >= 4) {
#pragma unroll
    for (int j = 0; j < KNN; ++j)
      tl[j * (4 * QPB) + (t - 4 * QPB)] = make_float2(dist[j], __int_as_float(idx[j]));
  }
  __syncthreads();
  if (t < QPB) {
    int p[5] = {0, 0, 0, 0, 0};  // 0 = al (chunks 0-3), 1..4 = chunks 4..7
    int* kn = knn + bq * KNN;
#pragma unroll 1
    for (int j = 0; j < KNN; ++j) {
      float bd;
      int bi, bc;
      {
        bool v = p[0] < KNN;
        int pp = v ? p[0] : 0;
        float2 e = al[pp * QPB + t];
        bd = v ? e.x : __builtin_inff();
        bi = __float_as_int(e.y);
        bc = 0;
      }
#pragma unroll
      for (int c = 0; c < 4; ++c) {
        bool v = p[c + 1] < KNN;
        int pp = v ? p[c + 1] : 0;
        float2 e = tl[pp * (4 * QPB) + t + c * QPB];
        float hd = v ? e.x : __builtin_inff();
        if (hd < bd) { bd = hd; bi = __float_as_int(e.y); bc = c + 1; }
      }
      kn[j] = bi;
#pragma unroll
      for (int c = 0; c < 5; ++c) p[c] += (bc == c);
    }
  }
}

__global__ void walk_kernel(const int* __restrict__ rand_k, const int* __restrict__ knn,
                            int* __restrict__ out) {
  int t = blockIdx.x * blockDim.x + threadIdx.x;
  if (t >= NB * NP) return;
  int b = t >> 13;
  int n = t & (NP - 1);
  int cur = n;
  int* o = out + t * CLEN;
  o[0] = cur;
#pragma unroll
  for (int l = 0; l < CLEN - 1; ++l) {
    int rk = rand_k[(l * NB + b) * NP + n];
    cur = knn[(b * NP + cur) * KNN + rk];
    o[l + 1] = cur;
  }
}

extern "C" void kernel_launch(void* const* d_in, const int* in_sizes, int n_in,
                              void* d_out, int out_size, void* d_ws, size_t ws_size,
                              hipStream_t stream) {
  const float* xyz = (const float*)d_in[0];
  const int* rand_k = (const int*)d_in[1];
  int* out = (int*)d_out;

  float4* cand = (float4*)d_ws;                                      // 512 KB
  int* knn = (int*)((char*)d_ws + (size_t)NB * NP * sizeof(float4)); // 2 MB

  prep_kernel<<<(NB * NP + 255) / 256, 256, 0, stream>>>(xyz, cand);
  knn_kernel<<<(NB * NP) / QPB, TPB, 0, stream>>>(cand, knn);
  walk_kernel<<<(NB * NP + 255) / 256, 256, 0, stream>>>(rand_k, knn, out);
}